// Round 1
// baseline (491.266 us; speedup 1.0000x reference)
//
#include <hip/hip_runtime.h>
#include <cmath>
#include <cstdint>

#define NB 8
#define NPTS 4096
#define NPOINT 204
#define NCENT (NB * NPOINT)   // 1632
#define NTASK (5 * NCENT)     // 8160

struct BallParams { float thr[5]; int ns[5]; float el; float denom; };
struct FinalParams { double w[5]; };

// ---------------------------------------------------------------------------
// Kernel 1: farthest point sampling, one block (512 threads) per batch.
// Bit-exact mirror of the reference f32 arithmetic (no FMA contraction),
// argmax with first-index tie-break.
// ---------------------------------------------------------------------------
__global__ __launch_bounds__(512) void fps_kernel(const float* __restrict__ pcd,
                                                  int* __restrict__ fps)
{
#pragma clang fp contract(off)
    __shared__ float sx[NPTS], sy[NPTS], sz[NPTS];
    __shared__ float rvv[8];
    __shared__ int   rii[8];
    __shared__ int   s_last;

    const int b = blockIdx.x;
    const int t = threadIdx.x;
    const float* base = pcd + (size_t)b * NPTS * 3;

    for (int j = t; j < NPTS; j += 512) {
        sx[j] = base[j * 3 + 0];
        sy[j] = base[j * 3 + 1];
        sz[j] = base[j * 3 + 2];
    }
    const int j0 = t * 8;
    float px[8], py[8], pz[8], md[8];
    for (int k = 0; k < 8; ++k) {
        px[k] = base[(j0 + k) * 3 + 0];
        py[k] = base[(j0 + k) * 3 + 1];
        pz[k] = base[(j0 + k) * 3 + 2];
        md[k] = 1e10f;
    }
    if (t == 0) fps[b * NPOINT] = 0;
    __syncthreads();

    int last = 0;
    const int lane = t & 63, wv = t >> 6;
    for (int it = 1; it < NPOINT; ++it) {
        const float lx = sx[last], ly = sy[last], lz = sz[last];
        float bv = -1.0f; int bi = NPTS;
        for (int k = 0; k < 8; ++k) {
            float dx = px[k] - lx, dy = py[k] - ly, dz = pz[k] - lz;
            float d = dx * dx + dy * dy;
            d = d + dz * dz;
            float m = md[k];
            m = fminf(m, d);
            md[k] = m;
            if (m > bv) { bv = m; bi = j0 + k; }   // k ascending -> first-max kept
        }
        // wave argmax (tie -> lowest index)
        for (int off = 32; off; off >>= 1) {
            float v2 = __shfl_down(bv, off);
            int   i2 = __shfl_down(bi, off);
            if (v2 > bv || (v2 == bv && i2 < bi)) { bv = v2; bi = i2; }
        }
        if (lane == 0) { rvv[wv] = bv; rii[wv] = bi; }
        __syncthreads();
        if (t == 0) {
            float Bv = rvv[0]; int Bi = rii[0];
            for (int w = 1; w < 8; ++w) {
                if (rvv[w] > Bv || (rvv[w] == Bv && rii[w] < Bi)) { Bv = rvv[w]; Bi = rii[w]; }
            }
            s_last = Bi;
            fps[b * NPOINT + it] = Bi;
        }
        __syncthreads();
        last = s_last;
    }
}

// ---------------------------------------------------------------------------
// Kernel 2: ball query + per-group uniform term. One wave per (p, center).
// ---------------------------------------------------------------------------
__global__ __launch_bounds__(256) void ball_kernel(const float* __restrict__ pcd,
                                                   const int* __restrict__ fps,
                                                   double* __restrict__ uvals,
                                                   BallParams P)
{
#pragma clang fp contract(off)
    __shared__ int wlist[4][64];

    const int wave = threadIdx.x >> 6;
    const int lane = threadIdx.x & 63;
    const int task = blockIdx.x * 4 + wave;      // NTASK = 8160 = 2040*4, exact

    const int pi = task / NCENT;
    const int c  = task % NCENT;
    const int b  = c / NPOINT;
    const int m  = c % NPOINT;
    const int   nsample = P.ns[pi];
    const float thr     = P.thr[pi];

    const float* base = pcd + (size_t)b * NPTS * 3;
    const int ci = fps[b * NPOINT + m];
    const float cx = base[ci * 3 + 0], cy = base[ci * 3 + 1], cz = base[ci * 3 + 2];
    const float cs = (cx * cx + cy * cy) + cz * cz;

    // scan points in ascending index order, collect first nsample inside ball
    int cnt = 0;
    for (int bj = 0; bj < NPTS; bj += 64) {
        const int j = bj + lane;
        const float qx = base[j * 3 + 0], qy = base[j * 3 + 1], qz = base[j * 3 + 2];
        const float qs  = (qx * qx + qy * qy) + qz * qz;
        const float dot = (cx * qx + cy * qy) + cz * qz;
        const float d = fmaxf((cs + qs) - 2.0f * dot, 0.0f);
        const bool q = d < thr;
        const unsigned long long bal = __ballot(q);
        if (q) {
            const int pos = cnt + __popcll(bal & ((1ull << lane) - 1ull));
            if (pos < nsample) wlist[wave][pos] = j;
        }
        cnt += __popcll(bal);
        if (cnt >= nsample) break;
    }
    const int m_in = (cnt < nsample) ? cnt : nsample;   // >= 1 (center qualifies, d==0)
    __syncthreads();

    // group phase: lane k holds group point k (padded with wlist[0])
    const int gidx = wlist[wave][(lane < m_in) ? lane : 0];
    const float gx = base[gidx * 3 + 0], gy = base[gidx * 3 + 1], gz = base[gidx * 3 + 2];
    const float gs = (gx * gx + gy * gy) + gz * gz;

    float m1 = 3.0e38f, m2 = 3.0e38f;
    for (int j = 0; j < nsample; ++j) {
        const float ox = __shfl(gx, j), oy = __shfl(gy, j), oz = __shfl(gz, j);
        const float os = __shfl(gs, j);
        const float dot = (gx * ox + gy * oy) + gz * oz;
        const float d = fmaxf((gs + os) - 2.0f * dot, 0.0f);
        if (d < m1) { m2 = m1; m1 = d; }
        else if (d < m2) { m2 = d; }
    }
    float ud = (lane < nsample) ? fabsf(sqrtf(m2 + 1e-12f) + 1e-8f) : 0.0f;
    for (int off = 32; off; off >>= 1) ud += __shfl_xor(ud, off);
    if (lane == 0) {
        const float um   = ud / (float)nsample;
        const float diff = um - P.el;
        const float u    = (diff * diff) / P.denom;
        uvals[pi * NCENT + c] = (double)u;
    }
}

// ---------------------------------------------------------------------------
// Kernel 3: repulsion loss. Grid = NB*64 blocks; block stages one batch in LDS;
// each wave handles 16 points; only sqd < h pairs matter (rare).
// ---------------------------------------------------------------------------
__global__ __launch_bounds__(256) void rep_kernel(const float* __restrict__ pcd,
                                                  double* __restrict__ part)
{
#pragma clang fp contract(off)
    __shared__ float sx[NPTS], sy[NPTS], sz[NPTS];
    __shared__ double wsum[4];

    const int batch = blockIdx.x >> 6;
    const int chunk = blockIdx.x & 63;
    const float* base = pcd + (size_t)batch * NPTS * 3;
    const int t = threadIdx.x;

    for (int j = t; j < NPTS; j += 256) {
        sx[j] = base[j * 3 + 0];
        sy[j] = base[j * 3 + 1];
        sz[j] = base[j * 3 + 2];
    }
    __syncthreads();

    const int wave = t >> 6, lane = t & 63;
    const float h = 0.0005f;
    double acc = 0.0;

    for (int ii = 0; ii < 16; ++ii) {
        const int i = (chunk << 6) + (wave << 4) + ii;
        const float cx = sx[i], cy = sy[i], cz = sz[i];
        const float cs = (cx * cx + cy * cy) + cz * cz;
        float s0 = 3e38f, s1 = 3e38f, s2 = 3e38f, s3 = 3e38f;
        for (int bj = 0; bj < NPTS; bj += 64) {
            const int j = bj + lane;
            const float qx = sx[j], qy = sy[j], qz = sz[j];
            const float qs  = (qx * qx + qy * qy) + qz * qz;
            const float dot = (cx * qx + cy * qy) + cz * qz;
            const float d = fmaxf((cs + qs) - 2.0f * dot, 0.0f);
            const bool q = (d < h) && (j != i);
            unsigned long long bal = __ballot(q);
            while (bal) {
                const int src = __ffsll((unsigned long long)bal) - 1;
                bal &= bal - 1;
                const float dv = __shfl(d, src);
                if (dv < s0) { s3 = s2; s2 = s1; s1 = s0; s0 = dv; }
                else if (dv < s1) { s3 = s2; s2 = s1; s1 = dv; }
                else if (dv < s2) { s3 = s2; s2 = dv; }
                else if (dv < s3) { s3 = dv; }
            }
        }
        if (lane == 0) {
            if (s0 < h) acc += (double)(h - s0);
            if (s1 < h) acc += (double)(h - s1);
            if (s2 < h) acc += (double)(h - s2);
            if (s3 < h) acc += (double)(h - s3);
        }
    }
    if (lane == 0) wsum[wave] = acc;
    __syncthreads();
    if (t == 0) part[blockIdx.x] = ((wsum[0] + wsum[1]) + wsum[2]) + wsum[3];
}

// ---------------------------------------------------------------------------
// Kernel 4: deterministic final reduction + loss assembly.
// ---------------------------------------------------------------------------
__global__ __launch_bounds__(256) void final_kernel(const double* __restrict__ uvals,
                                                    const double* __restrict__ part,
                                                    float* __restrict__ out,
                                                    FinalParams F)
{
    __shared__ double red[256];
    const int t = threadIdx.x;
    double sums[6];

    for (int p = 0; p < 5; ++p) {
        double s = 0.0;
        for (int c = t; c < NCENT; c += 256) s += uvals[p * NCENT + c];
        red[t] = s;
        __syncthreads();
        for (int o = 128; o; o >>= 1) {
            if (t < o) red[t] += red[t + o];
            __syncthreads();
        }
        if (t == 0) sums[p] = red[0];
        __syncthreads();
    }
    {
        double s = 0.0;
        for (int c = t; c < NB * 64; c += 256) s += part[c];
        red[t] = s;
        __syncthreads();
        for (int o = 128; o; o >>= 1) {
            if (t < o) red[t] += red[t + o];
            __syncthreads();
        }
        if (t == 0) sums[5] = red[0];
    }
    if (t == 0) {
        double loss = 0.0;
        loss += (sums[0] / (double)NCENT) * F.w[0];
        loss += (sums[1] / (double)NCENT) * F.w[1];
        loss += (sums[2] / (double)NCENT) * F.w[2];
        loss += (sums[3] / (double)NCENT) * F.w[3];
        loss += (sums[4] / (double)NCENT) * F.w[4];
        loss /= 5.0;
        const double rep = sums[5] / (double)(NB * NPTS * 4);
        out[0] = (float)(loss + rep);
    }
}

// ---------------------------------------------------------------------------
extern "C" void kernel_launch(void* const* d_in, const int* in_sizes, int n_in,
                              void* d_out, int out_size, void* d_ws, size_t ws_size,
                              hipStream_t stream)
{
    const float* pcd = (const float*)d_in[0];
    float* out = (float*)d_out;

    // workspace layout
    int*    fps   = (int*)d_ws;                                   // NB*NPOINT ints
    double* uvals = (double*)((char*)d_ws + 8192);                // 5*NCENT doubles
    double* repp  = (double*)((char*)d_ws + 8192 + (size_t)5 * NCENT * 8); // NB*64 doubles

    const double pv[5] = {0.004, 0.006, 0.008, 0.01, 0.012};
    const int    nsv[5] = {16, 24, 32, 40, 49};

    BallParams bp;
    FinalParams fp;
    for (int i = 0; i < 5; ++i) {
        const double r = sqrt(pv[i]);       // math.sqrt(p * 1.0)
        bp.thr[i] = (float)(r * r);         // f32(r*r), as jax weak-type cast
        bp.ns[i]  = nsv[i];
        const double w = pv[i] * 100.0;
        fp.w[i] = w * w;
    }
    const double el = sqrt(3.141592653589793 / 4096.0);
    bp.el    = (float)el;
    bp.denom = (float)(el + 1e-8);

    fps_kernel<<<NB, 512, 0, stream>>>(pcd, fps);
    ball_kernel<<<NTASK / 4, 256, 0, stream>>>(pcd, fps, uvals, bp);
    rep_kernel<<<NB * 64, 256, 0, stream>>>(pcd, repp);
    final_kernel<<<1, 256, 0, stream>>>(uvals, repp, out, fp);
}

// Round 2
// 300.327 us; speedup vs baseline: 1.6358x; 1.6358x over previous
//
#include <hip/hip_runtime.h>
#include <cmath>
#include <cstdint>

#define NB 8
#define NPTS 4096
#define NPOINT 204
#define NCENT (NB * NPOINT)   // 1632
#define NTASK (5 * NCENT)     // 8160

struct BallParams { float thr[5]; int ns[5]; float el; float denom; };
struct FinalParams { double w[5]; };

// ---------------------------------------------------------------------------
// DPP wave-64 reductions (row_shr 1/2/4/8 + row_bcast15/31 -> lane 63 holds
// the result). bound_ctrl=false with old=self => invalid lanes are identity.
// ---------------------------------------------------------------------------
template<int CTRL, int RMASK>
__device__ __forceinline__ float dpp_fmax_step(float v) {
    int iv = __float_as_int(v);
    int mv = __builtin_amdgcn_update_dpp(iv, iv, CTRL, RMASK, 0xF, false);
    return fmaxf(v, __int_as_float(mv));
}
__device__ __forceinline__ float wave_fmax63(float v) {
    v = dpp_fmax_step<0x111, 0xF>(v);   // row_shr:1
    v = dpp_fmax_step<0x112, 0xF>(v);   // row_shr:2
    v = dpp_fmax_step<0x114, 0xF>(v);   // row_shr:4
    v = dpp_fmax_step<0x118, 0xF>(v);   // row_shr:8
    v = dpp_fmax_step<0x142, 0xA>(v);   // row_bcast:15 -> rows 1,3
    v = dpp_fmax_step<0x143, 0xC>(v);   // row_bcast:31 -> rows 2,3
    return v;                            // lane 63 = wave max
}
template<int CTRL, int RMASK>
__device__ __forceinline__ unsigned dpp_umin_step(unsigned v) {
    int mv = __builtin_amdgcn_update_dpp((int)v, (int)v, CTRL, RMASK, 0xF, false);
    unsigned u = (unsigned)mv;
    return u < v ? u : v;
}
__device__ __forceinline__ unsigned wave_umin63(unsigned v) {
    v = dpp_umin_step<0x111, 0xF>(v);
    v = dpp_umin_step<0x112, 0xF>(v);
    v = dpp_umin_step<0x114, 0xF>(v);
    v = dpp_umin_step<0x118, 0xF>(v);
    v = dpp_umin_step<0x142, 0xA>(v);
    v = dpp_umin_step<0x143, 0xC>(v);
    return v;                            // lane 63 = wave min
}

// ---------------------------------------------------------------------------
// Fused kernel: blocks 0..7 do FPS (one batch each, 4 waves, 16 pts/lane);
// blocks 8..519 do the repulsion loss (independent of FPS).
// ---------------------------------------------------------------------------
__global__ __launch_bounds__(256) void fused_fps_rep(const float* __restrict__ pcd,
                                                     int* __restrict__ fps,
                                                     double* __restrict__ part)
{
#pragma clang fp contract(off)
    __shared__ float4 spts[NPTS];                       // 64 KiB
    __shared__ __align__(16) uint2 exch[2][4];
    __shared__ double wsum[4];

    const int t = threadIdx.x;

    if (blockIdx.x < NB) {
        // ------------------------------ FPS ------------------------------
        const int b = blockIdx.x;
        const float* base = pcd + (size_t)b * NPTS * 3;

        for (int j = t; j < NPTS; j += 256)
            spts[j] = make_float4(base[3*j], base[3*j+1], base[3*j+2], 0.f);

        const int pbase = t * 16;
        float px[16], py[16], pz[16], md[16];
#pragma unroll
        for (int k = 0; k < 16; ++k) {
            px[k] = base[(pbase + k) * 3 + 0];
            py[k] = base[(pbase + k) * 3 + 1];
            pz[k] = base[(pbase + k) * 3 + 2];
            md[k] = 1e10f;
        }
        if (t == 0) fps[b * NPOINT] = 0;
        __syncthreads();

        const int lane = t & 63, wv = t >> 6;
        float lx = spts[0].x, ly = spts[0].y, lz = spts[0].z;

        for (int it = 1; it < NPOINT; ++it) {
            // update min-dists (bit-exact: (dx^2+dy^2)+dz^2, fminf)
#pragma unroll
            for (int k = 0; k < 16; ++k) {
                float dx = px[k] - lx, dy = py[k] - ly, dz = pz[k] - lz;
                float d = dx * dx + dy * dy;
                d = d + dz * dz;
                md[k] = fminf(md[k], d);
            }
            // per-lane value max (tree)
            float m8[8], m4[4], m2[2];
#pragma unroll
            for (int k = 0; k < 8; ++k) m8[k] = fmaxf(md[k], md[k + 8]);
#pragma unroll
            for (int k = 0; k < 4; ++k) m4[k] = fmaxf(m8[k], m8[k + 4]);
            m2[0] = fmaxf(m4[0], m4[2]); m2[1] = fmaxf(m4[1], m4[3]);
            float vm = fmaxf(m2[0], m2[1]);
            // wave max -> lane63, broadcast via readlane
            float vml = wave_fmax63(vm);
            float wm = __int_as_float(__builtin_amdgcn_readlane(__float_as_int(vml), 63));
            // first (lowest) index equal to wave max: u32 min tree over candidates
            unsigned c8[8], c4[4], c2[2];
#pragma unroll
            for (int k = 0; k < 8; ++k) {
                unsigned a  = (md[k]     == wm) ? (unsigned)(pbase + k)     : 0xFFFFFFFFu;
                unsigned bq = (md[k + 8] == wm) ? (unsigned)(pbase + k + 8) : 0xFFFFFFFFu;
                c8[k] = a < bq ? a : bq;
            }
#pragma unroll
            for (int k = 0; k < 4; ++k) c4[k] = c8[k] < c8[k + 4] ? c8[k] : c8[k + 4];
            c2[0] = c4[0] < c4[2] ? c4[0] : c4[2];
            c2[1] = c4[1] < c4[3] ? c4[1] : c4[3];
            unsigned ci = c2[0] < c2[1] ? c2[0] : c2[1];
            unsigned widx = wave_umin63(ci);

            if (lane == 63) exch[it & 1][wv] = make_uint2(__float_as_uint(vml), widx);
            __syncthreads();

            const uint4* e = (const uint4*)&exch[it & 1][0];
            uint4 A = e[0], B = e[1];
            unsigned bv = A.x, bi = A.y;
            if (A.z > bv || (A.z == bv && A.w < bi)) { bv = A.z; bi = A.w; }
            if (B.x > bv || (B.x == bv && B.y < bi)) { bv = B.x; bi = B.y; }
            if (B.z > bv || (B.z == bv && B.w < bi)) { bv = B.z; bi = B.w; }

            if (t == 0) fps[b * NPOINT + it] = (int)bi;
            float4 cc = spts[bi];
            lx = cc.x; ly = cc.y; lz = cc.z;
        }
    } else {
        // --------------------------- repulsion ---------------------------
        float* sx = (float*)spts;          // carve 48 KiB from spts
        float* sy = sx + NPTS;
        float* sz = sy + NPTS;

        const int bb = blockIdx.x - NB;
        const int batch = bb >> 6;
        const int chunk = bb & 63;
        const float* base = pcd + (size_t)batch * NPTS * 3;

        for (int j = t; j < NPTS; j += 256) {
            sx[j] = base[j * 3 + 0];
            sy[j] = base[j * 3 + 1];
            sz[j] = base[j * 3 + 2];
        }
        __syncthreads();

        const int wave = t >> 6, lane = t & 63;
        const float h = 0.0005f;
        double acc = 0.0;

        for (int ii = 0; ii < 16; ++ii) {
            const int i = (chunk << 6) + (wave << 4) + ii;
            const float cx = sx[i], cy = sy[i], cz = sz[i];
            const float cs = (cx * cx + cy * cy) + cz * cz;
            float s0 = 3e38f, s1 = 3e38f, s2 = 3e38f, s3 = 3e38f;
            for (int bj = 0; bj < NPTS; bj += 64) {
                const int j = bj + lane;
                const float qx = sx[j], qy = sy[j], qz = sz[j];
                const float qs  = (qx * qx + qy * qy) + qz * qz;
                const float dot = (cx * qx + cy * qy) + cz * qz;
                const float d = fmaxf((cs + qs) - 2.0f * dot, 0.0f);
                const bool q = (d < h) && (j != i);
                unsigned long long bal = __ballot(q);
                while (bal) {
                    const int src = __ffsll((unsigned long long)bal) - 1;
                    bal &= bal - 1;
                    const float dv = __shfl(d, src);
                    if (dv < s0) { s3 = s2; s2 = s1; s1 = s0; s0 = dv; }
                    else if (dv < s1) { s3 = s2; s2 = s1; s1 = dv; }
                    else if (dv < s2) { s3 = s2; s2 = dv; }
                    else if (dv < s3) { s3 = dv; }
                }
            }
            if (lane == 0) {
                if (s0 < h) acc += (double)(h - s0);
                if (s1 < h) acc += (double)(h - s1);
                if (s2 < h) acc += (double)(h - s2);
                if (s3 < h) acc += (double)(h - s3);
            }
        }
        if (lane == 0) wsum[wave] = acc;
        __syncthreads();
        if (t == 0) part[bb] = ((wsum[0] + wsum[1]) + wsum[2]) + wsum[3];
    }
}

// ---------------------------------------------------------------------------
// Ball query + per-group uniform term. One wave per (p, center).
// ---------------------------------------------------------------------------
__global__ __launch_bounds__(256) void ball_kernel(const float* __restrict__ pcd,
                                                   const int* __restrict__ fps,
                                                   double* __restrict__ uvals,
                                                   BallParams P)
{
#pragma clang fp contract(off)
    __shared__ int wlist[4][64];

    const int wave = threadIdx.x >> 6;
    const int lane = threadIdx.x & 63;
    const int task = blockIdx.x * 4 + wave;      // NTASK = 8160 = 2040*4

    const int pi = task / NCENT;
    const int c  = task % NCENT;
    const int b  = c / NPOINT;
    const int m  = c % NPOINT;
    const int   nsample = P.ns[pi];
    const float thr     = P.thr[pi];

    const float* base = pcd + (size_t)b * NPTS * 3;
    const int ci = fps[b * NPOINT + m];
    const float cx = base[ci * 3 + 0], cy = base[ci * 3 + 1], cz = base[ci * 3 + 2];
    const float cs = (cx * cx + cy * cy) + cz * cz;

    int cnt = 0;
    for (int bj = 0; bj < NPTS; bj += 64) {
        const int j = bj + lane;
        const float qx = base[j * 3 + 0], qy = base[j * 3 + 1], qz = base[j * 3 + 2];
        const float qs  = (qx * qx + qy * qy) + qz * qz;
        const float dot = (cx * qx + cy * qy) + cz * qz;
        const float d = fmaxf((cs + qs) - 2.0f * dot, 0.0f);
        const bool q = d < thr;
        const unsigned long long bal = __ballot(q);
        if (q) {
            const int pos = cnt + __popcll(bal & ((1ull << lane) - 1ull));
            if (pos < nsample) wlist[wave][pos] = j;
        }
        cnt += __popcll(bal);
        if (cnt >= nsample) break;
    }
    const int m_in = (cnt < nsample) ? cnt : nsample;
    __syncthreads();

    const int gidx = wlist[wave][(lane < m_in) ? lane : 0];
    const float gx = base[gidx * 3 + 0], gy = base[gidx * 3 + 1], gz = base[gidx * 3 + 2];
    const float gs = (gx * gx + gy * gy) + gz * gz;

    float m1 = 3.0e38f, m2 = 3.0e38f;
    for (int j = 0; j < nsample; ++j) {
        const float ox = __shfl(gx, j), oy = __shfl(gy, j), oz = __shfl(gz, j);
        const float os = __shfl(gs, j);
        const float dot = (gx * ox + gy * oy) + gz * oz;
        const float d = fmaxf((gs + os) - 2.0f * dot, 0.0f);
        if (d < m1) { m2 = m1; m1 = d; }
        else if (d < m2) { m2 = d; }
    }
    float ud = (lane < nsample) ? fabsf(sqrtf(m2 + 1e-12f) + 1e-8f) : 0.0f;
    for (int off = 32; off; off >>= 1) ud += __shfl_xor(ud, off);
    if (lane == 0) {
        const float um   = ud / (float)nsample;
        const float diff = um - P.el;
        const float u    = (diff * diff) / P.denom;
        uvals[pi * NCENT + c] = (double)u;
    }
}

// ---------------------------------------------------------------------------
// Deterministic final reduction + loss assembly.
// ---------------------------------------------------------------------------
__global__ __launch_bounds__(256) void final_kernel(const double* __restrict__ uvals,
                                                    const double* __restrict__ part,
                                                    float* __restrict__ out,
                                                    FinalParams F)
{
    __shared__ double red[256];
    const int t = threadIdx.x;
    double sums[6];

    for (int p = 0; p < 5; ++p) {
        double s = 0.0;
        for (int c = t; c < NCENT; c += 256) s += uvals[p * NCENT + c];
        red[t] = s;
        __syncthreads();
        for (int o = 128; o; o >>= 1) {
            if (t < o) red[t] += red[t + o];
            __syncthreads();
        }
        if (t == 0) sums[p] = red[0];
        __syncthreads();
    }
    {
        double s = 0.0;
        for (int c = t; c < NB * 64; c += 256) s += part[c];
        red[t] = s;
        __syncthreads();
        for (int o = 128; o; o >>= 1) {
            if (t < o) red[t] += red[t + o];
            __syncthreads();
        }
        if (t == 0) sums[5] = red[0];
    }
    if (t == 0) {
        double loss = 0.0;
        loss += (sums[0] / (double)NCENT) * F.w[0];
        loss += (sums[1] / (double)NCENT) * F.w[1];
        loss += (sums[2] / (double)NCENT) * F.w[2];
        loss += (sums[3] / (double)NCENT) * F.w[3];
        loss += (sums[4] / (double)NCENT) * F.w[4];
        loss /= 5.0;
        const double rep = sums[5] / (double)(NB * NPTS * 4);
        out[0] = (float)(loss + rep);
    }
}

// ---------------------------------------------------------------------------
extern "C" void kernel_launch(void* const* d_in, const int* in_sizes, int n_in,
                              void* d_out, int out_size, void* d_ws, size_t ws_size,
                              hipStream_t stream)
{
    const float* pcd = (const float*)d_in[0];
    float* out = (float*)d_out;

    int*    fps   = (int*)d_ws;                                   // NB*NPOINT ints
    double* uvals = (double*)((char*)d_ws + 8192);                // 5*NCENT doubles
    double* repp  = (double*)((char*)d_ws + 8192 + (size_t)5 * NCENT * 8); // NB*64 doubles

    const double pv[5] = {0.004, 0.006, 0.008, 0.01, 0.012};
    const int    nsv[5] = {16, 24, 32, 40, 49};

    BallParams bp;
    FinalParams fp;
    for (int i = 0; i < 5; ++i) {
        const double r = sqrt(pv[i]);
        bp.thr[i] = (float)(r * r);
        bp.ns[i]  = nsv[i];
        const double w = pv[i] * 100.0;
        fp.w[i] = w * w;
    }
    const double el = sqrt(3.141592653589793 / 4096.0);
    bp.el    = (float)el;
    bp.denom = (float)(el + 1e-8);

    fused_fps_rep<<<NB + NB * 64, 256, 0, stream>>>(pcd, fps, repp);
    ball_kernel<<<NTASK / 4, 256, 0, stream>>>(pcd, fps, uvals, bp);
    final_kernel<<<1, 256, 0, stream>>>(uvals, repp, out, fp);
}

// Round 3
// 293.909 us; speedup vs baseline: 1.6715x; 1.0218x over previous
//
#include <hip/hip_runtime.h>
#include <cmath>
#include <cstdint>

#define NB 8
#define NPTS 4096
#define NPOINT 204
#define NCENT (NB * NPOINT)   // 1632
#define NTASK (5 * NCENT)     // 8160

typedef float v2f __attribute__((ext_vector_type(2)));
typedef unsigned long long u64;

struct BallParams { float thr[5]; int ns[5]; float el; float denom; };
struct FinalParams { double w[5]; };

// ---------------------------------------------------------------------------
// u64 max DPP reduction: row_shr 1/2/4/8 + row_bcast15/31 -> lane 63 holds max.
// bound_ctrl=false, old=self => invalid source lanes act as identity.
// ---------------------------------------------------------------------------
template<int CTRL, int RMASK>
__device__ __forceinline__ u64 dpp_u64max_step(u64 v) {
    const int lo = (int)(unsigned)v, hi = (int)(unsigned)(v >> 32);
    const int lo2 = __builtin_amdgcn_update_dpp(lo, lo, CTRL, RMASK, 0xF, false);
    const int hi2 = __builtin_amdgcn_update_dpp(hi, hi, CTRL, RMASK, 0xF, false);
    const u64 o = ((u64)(unsigned)hi2 << 32) | (unsigned)lo2;
    return o > v ? o : v;
}
__device__ __forceinline__ u64 wave_u64max63(u64 v) {
    v = dpp_u64max_step<0x111, 0xF>(v);   // row_shr:1
    v = dpp_u64max_step<0x112, 0xF>(v);   // row_shr:2
    v = dpp_u64max_step<0x114, 0xF>(v);   // row_shr:4
    v = dpp_u64max_step<0x118, 0xF>(v);   // row_shr:8
    v = dpp_u64max_step<0x142, 0xA>(v);   // row_bcast:15
    v = dpp_u64max_step<0x143, 0xC>(v);   // row_bcast:31
    return v;                              // lane 63 = wave max
}

// ---------------------------------------------------------------------------
// Fused: blocks 0..7 FPS (one batch each, 4 waves, 16 pts/lane);
// blocks 8..519 repulsion. No VMEM inside the FPS loop.
// ---------------------------------------------------------------------------
__global__ __launch_bounds__(256) void fused_fps_rep(const float* __restrict__ pcd,
                                                     int* __restrict__ fps,
                                                     double* __restrict__ part)
{
#pragma clang fp contract(off)
    __shared__ float4 spts[NPTS];                 // 64 KiB (rep branch reuses)
    __shared__ int fps_lds[NPOINT];
    __shared__ __align__(16) u64 exch[2][4];
    __shared__ double wsum[4];

    const int t = threadIdx.x;

    if (blockIdx.x < NB) {
        // ------------------------------ FPS ------------------------------
        const int b = blockIdx.x;
        const float* base = pcd + (size_t)b * NPTS * 3;

        for (int j = t; j < NPTS; j += 256)
            spts[j] = make_float4(base[3*j], base[3*j+1], base[3*j+2], 0.f);

        const int pbase = t * 16;
        v2f px2[8], py2[8], pz2[8], md2[8];
        unsigned lo_c[16];
#pragma unroll
        for (int i = 0; i < 8; ++i) {
            const int k0 = pbase + 2 * i, k1 = k0 + 1;
            px2[i] = (v2f){ base[k0*3+0], base[k1*3+0] };
            py2[i] = (v2f){ base[k0*3+1], base[k1*3+1] };
            pz2[i] = (v2f){ base[k0*3+2], base[k1*3+2] };
            md2[i] = (v2f){ 1e10f, 1e10f };
            lo_c[2*i]   = (unsigned)(4095 - k0);
            lo_c[2*i+1] = (unsigned)(4095 - k1);
        }
        if (t == 0) fps_lds[0] = 0;
        __syncthreads();

        const int lane = t & 63, wv = t >> 6;
        float lx = spts[0].x, ly = spts[0].y, lz = spts[0].z;

        for (int it = 1; it < NPOINT; ++it) {
            const v2f lx2 = (v2f){lx, lx}, ly2 = (v2f){ly, ly}, lz2 = (v2f){lz, lz};
            u64 c[16];
            // dist update: exact per-element (dx^2+dy^2)+dz^2, fminf
#pragma unroll
            for (int i = 0; i < 8; ++i) {
                const v2f dx = px2[i] - lx2, dy = py2[i] - ly2, dz = pz2[i] - lz2;
                v2f d = dx * dx + dy * dy;
                d = d + dz * dz;
                v2f m = md2[i];
                m.x = fminf(m.x, d.x);
                m.y = fminf(m.y, d.y);
                md2[i] = m;
                c[2*i]   = ((u64)(unsigned)__float_as_int(m.x) << 32) | lo_c[2*i];
                c[2*i+1] = ((u64)(unsigned)__float_as_int(m.y) << 32) | lo_c[2*i+1];
            }
            // per-lane u64 max tree (value-major, tie -> lowest index)
#pragma unroll
            for (int s = 8; s >= 1; s >>= 1)
#pragma unroll
                for (int i = 0; i < 16; ++i)
                    if (i < s) c[i] = c[i] > c[i + s] ? c[i] : c[i + s];
            const u64 wmax = wave_u64max63(c[0]);

            if (lane == 63) exch[it & 1][wv] = wmax;
            __syncthreads();

            const ulonglong2* e = (const ulonglong2*)&exch[it & 1][0];
            const ulonglong2 e0 = e[0], e1 = e[1];
            u64 m = e0.x;
            m = e0.y > m ? e0.y : m;
            m = e1.x > m ? e1.x : m;
            m = e1.y > m ? e1.y : m;
            const int bi = 4095 - (int)((unsigned)m & 0xFFFu);

            if (t == 0) fps_lds[it] = bi;
            const float4 cc = spts[bi];
            lx = cc.x; ly = cc.y; lz = cc.z;
        }
        __syncthreads();
        for (int j = t; j < NPOINT; j += 256) fps[b * NPOINT + j] = fps_lds[j];
    } else {
        // --------------------------- repulsion ---------------------------
        float* sx = (float*)spts;          // carve 48 KiB
        float* sy = sx + NPTS;
        float* sz = sy + NPTS;

        const int bb = blockIdx.x - NB;
        const int batch = bb >> 6;
        const int chunk = bb & 63;
        const float* base = pcd + (size_t)batch * NPTS * 3;

        for (int j = t; j < NPTS; j += 256) {
            sx[j] = base[j * 3 + 0];
            sy[j] = base[j * 3 + 1];
            sz[j] = base[j * 3 + 2];
        }
        __syncthreads();

        const int wave = t >> 6, lane = t & 63;
        const float h = 0.0005f;
        double acc = 0.0;

        for (int ii = 0; ii < 16; ++ii) {
            const int i = (chunk << 6) + (wave << 4) + ii;
            const float cx = sx[i], cy = sy[i], cz = sz[i];
            const float cs = (cx * cx + cy * cy) + cz * cz;
            float s0 = 3e38f, s1 = 3e38f, s2 = 3e38f, s3 = 3e38f;
            for (int bj = 0; bj < NPTS; bj += 64) {
                const int j = bj + lane;
                const float qx = sx[j], qy = sy[j], qz = sz[j];
                const float qs  = (qx * qx + qy * qy) + qz * qz;
                const float dot = (cx * qx + cy * qy) + cz * qz;
                const float d = fmaxf((cs + qs) - 2.0f * dot, 0.0f);
                const bool q = (d < h) && (j != i);
                unsigned long long bal = __ballot(q);
                while (bal) {
                    const int src = __ffsll((unsigned long long)bal) - 1;
                    bal &= bal - 1;
                    const float dv = __shfl(d, src);
                    if (dv < s0) { s3 = s2; s2 = s1; s1 = s0; s0 = dv; }
                    else if (dv < s1) { s3 = s2; s2 = s1; s1 = dv; }
                    else if (dv < s2) { s3 = s2; s2 = dv; }
                    else if (dv < s3) { s3 = dv; }
                }
            }
            if (lane == 0) {
                if (s0 < h) acc += (double)(h - s0);
                if (s1 < h) acc += (double)(h - s1);
                if (s2 < h) acc += (double)(h - s2);
                if (s3 < h) acc += (double)(h - s3);
            }
        }
        if (lane == 0) wsum[wave] = acc;
        __syncthreads();
        if (t == 0) part[bb] = ((wsum[0] + wsum[1]) + wsum[2]) + wsum[3];
    }
}

// ---------------------------------------------------------------------------
// Ball query + per-group uniform term. One wave per (p, center); waves
// independent (no block barrier). Group coords staged in per-wave LDS.
// ---------------------------------------------------------------------------
__global__ __launch_bounds__(256) void ball_kernel(const float* __restrict__ pcd,
                                                   const int* __restrict__ fps,
                                                   double* __restrict__ uvals,
                                                   BallParams P)
{
#pragma clang fp contract(off)
    __shared__ int wlist[4][64];
    __shared__ float4 gpts[4][64];

    const int wave = threadIdx.x >> 6;
    const int lane = threadIdx.x & 63;
    const int task = blockIdx.x * 4 + wave;      // NTASK = 8160 = 2040*4

    const int pi = task / NCENT;
    const int c  = task % NCENT;
    const int b  = c / NPOINT;
    const int m  = c % NPOINT;
    const int   nsample = P.ns[pi];
    const float thr     = P.thr[pi];

    const float* base = pcd + (size_t)b * NPTS * 3;
    const int ci = fps[b * NPOINT + m];
    const float cx = base[ci * 3 + 0], cy = base[ci * 3 + 1], cz = base[ci * 3 + 2];
    const float cs = (cx * cx + cy * cy) + cz * cz;

    int cnt = 0;
    for (int bj = 0; bj < NPTS; bj += 64) {
        const int j = bj + lane;
        const float qx = base[j * 3 + 0], qy = base[j * 3 + 1], qz = base[j * 3 + 2];
        const float qs  = (qx * qx + qy * qy) + qz * qz;
        const float dot = (cx * qx + cy * qy) + cz * qz;
        const float d = fmaxf((cs + qs) - 2.0f * dot, 0.0f);
        const bool q = d < thr;
        const unsigned long long bal = __ballot(q);
        if (q) {
            const int pos = cnt + __popcll(bal & ((1ull << lane) - 1ull));
            if (pos < nsample) wlist[wave][pos] = j;
        }
        cnt += __popcll(bal);
        if (cnt >= nsample) break;
    }
    const int m_in = (cnt < nsample) ? cnt : nsample;   // >= 1 (center is inside)

    const int gidx = wlist[wave][(lane < m_in) ? lane : 0];
    const float gx = base[gidx * 3 + 0], gy = base[gidx * 3 + 1], gz = base[gidx * 3 + 2];
    const float gs = (gx * gx + gy * gy) + gz * gz;
    gpts[wave][lane] = make_float4(gx, gy, gz, gs);

    float m1 = 3.0e38f, m2 = 3.0e38f;
    for (int j = 0; j < nsample; ++j) {
        const float4 o = gpts[wave][j];
        const float dot = (gx * o.x + gy * o.y) + gz * o.z;
        const float d = fmaxf((gs + o.w) - 2.0f * dot, 0.0f);
        if (d < m1) { m2 = m1; m1 = d; }
        else if (d < m2) { m2 = d; }
    }
    float ud = (lane < nsample) ? fabsf(sqrtf(m2 + 1e-12f) + 1e-8f) : 0.0f;
    for (int off = 32; off; off >>= 1) ud += __shfl_xor(ud, off);
    if (lane == 0) {
        const float um   = ud / (float)nsample;
        const float diff = um - P.el;
        const float u    = (diff * diff) / P.denom;
        uvals[pi * NCENT + c] = (double)u;
    }
}

// ---------------------------------------------------------------------------
// Deterministic final reduction + loss assembly.
// ---------------------------------------------------------------------------
__global__ __launch_bounds__(256) void final_kernel(const double* __restrict__ uvals,
                                                    const double* __restrict__ part,
                                                    float* __restrict__ out,
                                                    FinalParams F)
{
    __shared__ double red[256];
    const int t = threadIdx.x;
    double sums[6];

    for (int p = 0; p < 5; ++p) {
        double s = 0.0;
        for (int c = t; c < NCENT; c += 256) s += uvals[p * NCENT + c];
        red[t] = s;
        __syncthreads();
        for (int o = 128; o; o >>= 1) {
            if (t < o) red[t] += red[t + o];
            __syncthreads();
        }
        if (t == 0) sums[p] = red[0];
        __syncthreads();
    }
    {
        double s = 0.0;
        for (int c = t; c < NB * 64; c += 256) s += part[c];
        red[t] = s;
        __syncthreads();
        for (int o = 128; o; o >>= 1) {
            if (t < o) red[t] += red[t + o];
            __syncthreads();
        }
        if (t == 0) sums[5] = red[0];
    }
    if (t == 0) {
        double loss = 0.0;
        loss += (sums[0] / (double)NCENT) * F.w[0];
        loss += (sums[1] / (double)NCENT) * F.w[1];
        loss += (sums[2] / (double)NCENT) * F.w[2];
        loss += (sums[3] / (double)NCENT) * F.w[3];
        loss += (sums[4] / (double)NCENT) * F.w[4];
        loss /= 5.0;
        const double rep = sums[5] / (double)(NB * NPTS * 4);
        out[0] = (float)(loss + rep);
    }
}

// ---------------------------------------------------------------------------
extern "C" void kernel_launch(void* const* d_in, const int* in_sizes, int n_in,
                              void* d_out, int out_size, void* d_ws, size_t ws_size,
                              hipStream_t stream)
{
    const float* pcd = (const float*)d_in[0];
    float* out = (float*)d_out;

    int*    fps   = (int*)d_ws;                                   // NB*NPOINT ints
    double* uvals = (double*)((char*)d_ws + 8192);                // 5*NCENT doubles
    double* repp  = (double*)((char*)d_ws + 8192 + (size_t)5 * NCENT * 8); // NB*64 doubles

    const double pv[5] = {0.004, 0.006, 0.008, 0.01, 0.012};
    const int    nsv[5] = {16, 24, 32, 40, 49};

    BallParams bp;
    FinalParams fp;
    for (int i = 0; i < 5; ++i) {
        const double r = sqrt(pv[i]);
        bp.thr[i] = (float)(r * r);
        bp.ns[i]  = nsv[i];
        const double w = pv[i] * 100.0;
        fp.w[i] = w * w;
    }
    const double el = sqrt(3.141592653589793 / 4096.0);
    bp.el    = (float)el;
    bp.denom = (float)(el + 1e-8);

    fused_fps_rep<<<NB + NB * 64, 256, 0, stream>>>(pcd, fps, repp);
    ball_kernel<<<NTASK / 4, 256, 0, stream>>>(pcd, fps, uvals, bp);
    final_kernel<<<1, 256, 0, stream>>>(uvals, repp, out, fp);
}

// Round 4
// 202.996 us; speedup vs baseline: 2.4201x; 1.4479x over previous
//
#include <hip/hip_runtime.h>
#include <cmath>
#include <cstdint>

#define NB 8
#define NPTS 4096
#define NPOINT 204
#define NCENT (NB * NPOINT)   // 1632
#define NTASK (5 * NCENT)     // 8160

typedef unsigned long long u64;

struct BallParams { float thr[5]; int ns[5]; float el; float denom; };
struct FinalParams { double w[5]; };

// ---------------------------------------------------------------------------
// u64 max DPP reduction: row_shr 1/2/4/8 + row_bcast15/31 -> lane 63 holds max.
// ---------------------------------------------------------------------------
template<int CTRL, int RMASK>
__device__ __forceinline__ u64 dpp_u64max_step(u64 v) {
    const int lo = (int)(unsigned)v, hi = (int)(unsigned)(v >> 32);
    const int lo2 = __builtin_amdgcn_update_dpp(lo, lo, CTRL, RMASK, 0xF, false);
    const int hi2 = __builtin_amdgcn_update_dpp(hi, hi, CTRL, RMASK, 0xF, false);
    const u64 o = ((u64)(unsigned)hi2 << 32) | (unsigned)lo2;
    return o > v ? o : v;
}
__device__ __forceinline__ u64 wave_u64max63(u64 v) {
    v = dpp_u64max_step<0x111, 0xF>(v);   // row_shr:1
    v = dpp_u64max_step<0x112, 0xF>(v);   // row_shr:2
    v = dpp_u64max_step<0x114, 0xF>(v);   // row_shr:4
    v = dpp_u64max_step<0x118, 0xF>(v);   // row_shr:8
    v = dpp_u64max_step<0x142, 0xA>(v);   // row_bcast:15
    v = dpp_u64max_step<0x143, 0xC>(v);   // row_bcast:31
    return v;                              // lane 63 = wave max
}
__device__ __forceinline__ u64 u64max(u64 a, u64 b) { return a > b ? a : b; }

// ---------------------------------------------------------------------------
// Fused: blocks 0..7 FPS (one batch, 8 waves, 8 pts/lane);
// blocks 8..519 repulsion (float4 LDS with precomputed |q|^2 in .w).
// ---------------------------------------------------------------------------
__global__ __launch_bounds__(512) void fused_fps_rep(const float* __restrict__ pcd,
                                                     int* __restrict__ fps,
                                                     double* __restrict__ part)
{
#pragma clang fp contract(off)
    __shared__ float4 spts[NPTS];                 // 64 KiB
    __shared__ int fps_lds[NPOINT];
    __shared__ __align__(16) u64 exch[2][8];
    __shared__ double wsum[8];

    const int t = threadIdx.x;
    const int lane = t & 63, wv = t >> 6;

    if (blockIdx.x < NB) {
        // ------------------------------ FPS ------------------------------
        const int b = blockIdx.x;
        const float* base = pcd + (size_t)b * NPTS * 3;

        for (int j = t; j < NPTS; j += 512)
            spts[j] = make_float4(base[3*j], base[3*j+1], base[3*j+2], 0.f);

        const int pbase = t * 8;
        float px[8], py[8], pz[8], md[8];
#pragma unroll
        for (int k = 0; k < 8; ++k) {
            px[k] = base[(pbase + k) * 3 + 0];
            py[k] = base[(pbase + k) * 3 + 1];
            pz[k] = base[(pbase + k) * 3 + 2];
            md[k] = 1e10f;
        }
        if (t == 0) fps_lds[0] = 0;
        __syncthreads();

        float lx = spts[0].x, ly = spts[0].y, lz = spts[0].z;

        for (int it = 1; it < NPOINT; ++it) {
            u64 c[8];
            // exact per-element: (dx^2+dy^2)+dz^2, fminf; pack (bits(md)<<32)|(4095-idx)
#pragma unroll
            for (int k = 0; k < 8; ++k) {
                const float dx = px[k] - lx, dy = py[k] - ly, dz = pz[k] - lz;
                float d = dx * dx + dy * dy;
                d = d + dz * dz;
                const float m = fminf(md[k], d);
                md[k] = m;
                c[k] = ((u64)(unsigned)__float_as_int(m) << 32)
                     | (unsigned)(4095 - (pbase + k));
            }
#pragma unroll
            for (int s = 4; s >= 1; s >>= 1)
#pragma unroll
                for (int i = 0; i < 8; ++i)
                    if (i < s) c[i] = u64max(c[i], c[i + s]);
            const u64 wmax = wave_u64max63(c[0]);

            if (lane == 63) exch[it & 1][wv] = wmax;
            __syncthreads();

            const ulonglong2* e = (const ulonglong2*)&exch[it & 1][0];
            const ulonglong2 E0 = e[0], E1 = e[1], E2 = e[2], E3 = e[3];
            u64 m01 = u64max(E0.x, E0.y), m23 = u64max(E1.x, E1.y);
            u64 m45 = u64max(E2.x, E2.y), m67 = u64max(E3.x, E3.y);
            const u64 m = u64max(u64max(m01, m23), u64max(m45, m67));
            const int bi = 4095 - (int)((unsigned)m & 0xFFFu);

            if (t == 0) fps_lds[it] = bi;
            const float4 cc = spts[bi];
            lx = cc.x; ly = cc.y; lz = cc.z;
        }
        __syncthreads();
        for (int j = t; j < NPOINT; j += 512) fps[b * NPOINT + j] = fps_lds[j];
    } else {
        // --------------------------- repulsion ---------------------------
        const int bb = blockIdx.x - NB;
        const int batch = bb >> 6;
        const int chunk = bb & 63;
        const float* base = pcd + (size_t)batch * NPTS * 3;

        for (int j = t; j < NPTS; j += 512) {
            const float x = base[j * 3 + 0], y = base[j * 3 + 1], z = base[j * 3 + 2];
            const float qs = (x * x + y * y) + z * z;
            spts[j] = make_float4(x, y, z, qs);
        }
        __syncthreads();

        const float h = 0.0005f;
        double acc = 0.0;

        for (int ii = 0; ii < 8; ++ii) {
            const int i = (chunk << 6) + (wv << 3) + ii;
            const float4 C = spts[i];
            const float cx = C.x, cy = C.y, cz = C.z, cs = C.w;
            float s0 = 3e38f, s1 = 3e38f, s2 = 3e38f, s3 = 3e38f;
            for (int bj = 0; bj < NPTS; bj += 64) {
                const int j = bj + lane;
                const float4 o = spts[j];
                const float dot = (cx * o.x + cy * o.y) + cz * o.z;
                const float d = fmaxf((cs + o.w) - 2.0f * dot, 0.0f);
                const bool q = (d < h) && (j != i);
                unsigned long long bal = __ballot(q);
                while (bal) {
                    const int src = __ffsll((unsigned long long)bal) - 1;
                    bal &= bal - 1;
                    const float dv = __shfl(d, src);
                    if (dv < s0) { s3 = s2; s2 = s1; s1 = s0; s0 = dv; }
                    else if (dv < s1) { s3 = s2; s2 = s1; s1 = dv; }
                    else if (dv < s2) { s3 = s2; s2 = dv; }
                    else if (dv < s3) { s3 = dv; }
                }
            }
            if (lane == 0) {
                if (s0 < h) acc += (double)(h - s0);
                if (s1 < h) acc += (double)(h - s1);
                if (s2 < h) acc += (double)(h - s2);
                if (s3 < h) acc += (double)(h - s3);
            }
        }
        if (lane == 0) wsum[wv] = acc;
        __syncthreads();
        if (t == 0) {
            double s = 0.0;
            for (int w = 0; w < 8; ++w) s += wsum[w];
            part[bb] = s;
        }
    }
}

// ---------------------------------------------------------------------------
// Ball query + per-group uniform term. 4 waves/block; all 4 tasks of a block
// share one (p, batch) since NPOINT%4==0 -> shared LDS staging of the batch.
// ---------------------------------------------------------------------------
__global__ __launch_bounds__(256) void ball_kernel(const float* __restrict__ pcd,
                                                   const int* __restrict__ fps,
                                                   double* __restrict__ uvals,
                                                   BallParams P)
{
#pragma clang fp contract(off)
    __shared__ float4 spts[NPTS];        // 64 KiB: x,y,z,|q|^2
    __shared__ int wlist[4][64];
    __shared__ float4 gpts[4][64];

    const int wave = threadIdx.x >> 6;
    const int lane = threadIdx.x & 63;
    const int task0 = blockIdx.x * 4;            // all 4 tasks: same pi, same b
    const int pi = task0 / NCENT;
    const int c0 = task0 % NCENT;
    const int b  = c0 / NPOINT;
    const int   nsample = P.ns[pi];
    const float thr     = P.thr[pi];

    const float* base = pcd + (size_t)b * NPTS * 3;
    for (int j = threadIdx.x; j < NPTS; j += 256) {
        const float x = base[j * 3 + 0], y = base[j * 3 + 1], z = base[j * 3 + 2];
        const float qs = (x * x + y * y) + z * z;
        spts[j] = make_float4(x, y, z, qs);
    }
    __syncthreads();

    const int c = c0 + wave;
    const int m = c % NPOINT;
    const int ci = fps[b * NPOINT + m];
    const float4 C = spts[ci];
    const float cx = C.x, cy = C.y, cz = C.z, cs = C.w;

    int cnt = 0;
    for (int bj = 0; bj < NPTS; bj += 64) {
        const int j = bj + lane;
        const float4 o = spts[j];
        const float dot = (cx * o.x + cy * o.y) + cz * o.z;
        const float d = fmaxf((cs + o.w) - 2.0f * dot, 0.0f);
        const bool q = d < thr;
        const unsigned long long bal = __ballot(q);
        if (q) {
            const int pos = cnt + __popcll(bal & ((1ull << lane) - 1ull));
            if (pos < nsample) wlist[wave][pos] = j;
        }
        cnt += __popcll(bal);
        if (cnt >= nsample) break;
    }
    const int m_in = (cnt < nsample) ? cnt : nsample;   // >= 1 (center inside)

    const int gidx = wlist[wave][(lane < m_in) ? lane : 0];
    const float4 G = spts[gidx];
    gpts[wave][lane] = G;
    const float gx = G.x, gy = G.y, gz = G.z, gs = G.w;

    float m1 = 3.0e38f, m2 = 3.0e38f;
    for (int j = 0; j < nsample; ++j) {
        const float4 o = gpts[wave][j];
        const float dot = (gx * o.x + gy * o.y) + gz * o.z;
        const float d = fmaxf((gs + o.w) - 2.0f * dot, 0.0f);
        if (d < m1) { m2 = m1; m1 = d; }
        else if (d < m2) { m2 = d; }
    }
    float ud = (lane < nsample) ? fabsf(sqrtf(m2 + 1e-12f) + 1e-8f) : 0.0f;
    for (int off = 32; off; off >>= 1) ud += __shfl_xor(ud, off);
    if (lane == 0) {
        const float um   = ud / (float)nsample;
        const float diff = um - P.el;
        const float u    = (diff * diff) / P.denom;
        uvals[pi * NCENT + c] = (double)u;
    }
}

// ---------------------------------------------------------------------------
// Deterministic final reduction + loss assembly.
// ---------------------------------------------------------------------------
__global__ __launch_bounds__(256) void final_kernel(const double* __restrict__ uvals,
                                                    const double* __restrict__ part,
                                                    float* __restrict__ out,
                                                    FinalParams F)
{
    __shared__ double red[256];
    const int t = threadIdx.x;
    double sums[6];

    for (int p = 0; p < 5; ++p) {
        double s = 0.0;
        for (int c = t; c < NCENT; c += 256) s += uvals[p * NCENT + c];
        red[t] = s;
        __syncthreads();
        for (int o = 128; o; o >>= 1) {
            if (t < o) red[t] += red[t + o];
            __syncthreads();
        }
        if (t == 0) sums[p] = red[0];
        __syncthreads();
    }
    {
        double s = 0.0;
        for (int c = t; c < NB * 64; c += 256) s += part[c];
        red[t] = s;
        __syncthreads();
        for (int o = 128; o; o >>= 1) {
            if (t < o) red[t] += red[t + o];
            __syncthreads();
        }
        if (t == 0) sums[5] = red[0];
    }
    if (t == 0) {
        double loss = 0.0;
        loss += (sums[0] / (double)NCENT) * F.w[0];
        loss += (sums[1] / (double)NCENT) * F.w[1];
        loss += (sums[2] / (double)NCENT) * F.w[2];
        loss += (sums[3] / (double)NCENT) * F.w[3];
        loss += (sums[4] / (double)NCENT) * F.w[4];
        loss /= 5.0;
        const double rep = sums[5] / (double)(NB * NPTS * 4);
        out[0] = (float)(loss + rep);
    }
}

// ---------------------------------------------------------------------------
extern "C" void kernel_launch(void* const* d_in, const int* in_sizes, int n_in,
                              void* d_out, int out_size, void* d_ws, size_t ws_size,
                              hipStream_t stream)
{
    const float* pcd = (const float*)d_in[0];
    float* out = (float*)d_out;

    int*    fps   = (int*)d_ws;                                   // NB*NPOINT ints
    double* uvals = (double*)((char*)d_ws + 8192);                // 5*NCENT doubles
    double* repp  = (double*)((char*)d_ws + 8192 + (size_t)5 * NCENT * 8); // NB*64 doubles

    const double pv[5] = {0.004, 0.006, 0.008, 0.01, 0.012};
    const int    nsv[5] = {16, 24, 32, 40, 49};

    BallParams bp;
    FinalParams fp;
    for (int i = 0; i < 5; ++i) {
        const double r = sqrt(pv[i]);
        bp.thr[i] = (float)(r * r);
        bp.ns[i]  = nsv[i];
        const double w = pv[i] * 100.0;
        fp.w[i] = w * w;
    }
    const double el = sqrt(3.141592653589793 / 4096.0);
    bp.el    = (float)el;
    bp.denom = (float)(el + 1e-8);

    fused_fps_rep<<<NB + NB * 64, 512, 0, stream>>>(pcd, fps, repp);
    ball_kernel<<<NTASK / 4, 256, 0, stream>>>(pcd, fps, uvals, bp);
    final_kernel<<<1, 256, 0, stream>>>(uvals, repp, out, fp);
}